// Round 1
// baseline (254.654 us; speedup 1.0000x reference)
//
#include <hip/hip_runtime.h>
#include <stdint.h>

// y[m][n] = sum_k x[m][k] * W[k][n] + b[n]
// M=262144, K=128, N=128. Memory-bound: 268 MB @ ~6.3 TB/s ~= 43 us floor.
// bf16 MFMA 16x16x32, operands swapped (A=W^T, B=x) so each lane's 4 C-regs
// are 4 CONSECUTIVE y columns -> f32x4 nontemporal stores (no write-allocate RMW).
//
// R1: latency-bound fix (was 30% HBM BW, 33% occupancy, all pipes idle):
//  - grid 1024 (exactly 4 blocks/CU, fully resident, no churn); each block
//    owns 256 rows = 4 iterations of 64 rows (16 rows/wave/iter).
//  - register double-buffer: issue next iter's 8x f32x4 x-loads BEFORE the
//    MFMA+store phase of the current iter; convert f32->bf16 at iter end.
//    Keeps ~8KB/wave of loads in flight under compute+store.

typedef __attribute__((ext_vector_type(8))) short bf16x8;   // 8 bf16 = 4 VGPRs
typedef __attribute__((ext_vector_type(4))) float f32x4;    // MFMA C/D

__device__ inline unsigned short f2bf(float f) {
  // round-to-nearest-even fp32 -> bf16 (inputs are finite normals)
  union { float f; uint32_t u; } v; v.f = f;
  uint32_t r = v.u + 0x7fffu + ((v.u >> 16) & 1u);
  return (unsigned short)(r >> 16);
}

__device__ inline bf16x8 cvt8(f32x4 a, f32x4 b) {
  bf16x8 r;
  r[0] = f2bf(a[0]); r[1] = f2bf(a[1]); r[2] = f2bf(a[2]); r[3] = f2bf(a[3]);
  r[4] = f2bf(b[0]); r[5] = f2bf(b[1]); r[6] = f2bf(b[2]); r[7] = f2bf(b[3]);
  return r;
}

__global__ __launch_bounds__(256, 4) void linear_kernel(
    const float* __restrict__ x, const float* __restrict__ w,
    const float* __restrict__ bias, float* __restrict__ y) {
  // W in A-fragment order (A = W^T tile):
  //   lds_w[((kk*8+nt)*64 + qk*16+lc)*8 + j] = bf16( W[kk*32+qk*8+j][nt*16+lc] )
  // i.e. A[m=lc][k=qk*8+j] = W[kk*32+k][nt*16+m]
  __shared__ __align__(16) unsigned short lds_w[128 * 128];

  const int t = threadIdx.x;

  // ---- stage W: column-wise scalar reads (L1/L2-hot, sector-coalesced),
  // ---- contiguous ds_write_b128 (conflict-free) ----
  #pragma unroll
  for (int gi = 0; gi < 8; ++gi) {
    int g = t + 256 * gi;            // group 0..2047; one group = 8 shorts = 16 B
    int fragid = g >> 6;             // kk*8+nt
    int slot   = g & 63;             // qk*16+lc
    int kk = fragid >> 3, nt = fragid & 7;
    int qk = slot >> 4,   lc = slot & 15;
    const float* wp = w + (size_t)(kk * 32 + qk * 8) * 128 + nt * 16 + lc;
    unsigned short tmp[8];
    #pragma unroll
    for (int j = 0; j < 8; ++j) tmp[j] = f2bf(wp[(size_t)j * 128]);
    *(bf16x8*)&lds_w[(size_t)g * 8] = *(const bf16x8*)tmp;
  }

  const int lane = t & 63;
  const int wave = t >> 6;
  const int col  = lane & 15;                  // y-row within 16-row tile
  const int quad = lane >> 4;

  // bias fragment: lane's 4 outputs are y cols nt*16 + quad*4 .. +3
  f32x4 bfrag[8];
  #pragma unroll
  for (int nt = 0; nt < 8; ++nt)
    bfrag[nt] = *(const f32x4*)(bias + nt * 16 + quad * 4);

  // 256 rows per block; wave handles rows [.. + wave*16 + col] over 4 iters
  const size_t row = (size_t)blockIdx.x * 256 + wave * 16 + col;
  const float* xp = x + row * 128 + quad * 8;
  float* yp = y + row * 128;

  // prologue: issue iter-0 loads before the barrier (latency overlaps staging)
  f32x4 buf[8];
  #pragma unroll
  for (int kk = 0; kk < 4; ++kk) {
    buf[2 * kk]     = *(const f32x4*)(xp + kk * 32);
    buf[2 * kk + 1] = *(const f32x4*)(xp + kk * 32 + 4);
  }

  __syncthreads();

  bf16x8 xf[4];
  #pragma unroll
  for (int kk = 0; kk < 4; ++kk) xf[kk] = cvt8(buf[2 * kk], buf[2 * kk + 1]);

  #pragma unroll
  for (int it = 0; it < 4; ++it) {
    // issue next iter's loads; they stay in flight under MFMA + stores below
    if (it < 3) {
      const float* xpn = xp + (size_t)(it + 1) * 64 * 128;
      #pragma unroll
      for (int kk = 0; kk < 4; ++kk) {
        buf[2 * kk]     = *(const f32x4*)(xpn + kk * 32);
        buf[2 * kk + 1] = *(const f32x4*)(xpn + kk * 32 + 4);
      }
    }

    float* ypi = yp + (size_t)it * 64 * 128;
    #pragma unroll
    for (int nt = 0; nt < 8; ++nt) {
      f32x4 acc = bfrag[nt];
      #pragma unroll
      for (int kk = 0; kk < 4; ++kk) {
        bf16x8 wf = *(const bf16x8*)&lds_w[((kk * 8 + nt) * 64 + lane) * 8];
        // D = (W tile)^T . (x tile)^T : D[m][n] = y[row+?][nt*16+m]
        acc = __builtin_amdgcn_mfma_f32_16x16x32_bf16(wf, xf[kk], acc, 0, 0, 0);
      }
      // lane stores y[row..][nt*16 + quad*4 .. +3] as one f32x4, streaming
      __builtin_nontemporal_store(acc, (f32x4*)(ypi + nt * 16 + quad * 4));
    }

    // convert the prefetched chunk for the next iteration (waits on its loads)
    if (it < 3) {
      #pragma unroll
      for (int kk = 0; kk < 4; ++kk) xf[kk] = cvt8(buf[2 * kk], buf[2 * kk + 1]);
    }
  }
}

extern "C" void kernel_launch(void* const* d_in, const int* in_sizes, int n_in,
                              void* d_out, int out_size, void* d_ws, size_t ws_size,
                              hipStream_t stream) {
  const float* x    = (const float*)d_in[0];
  const float* w    = (const float*)d_in[1];
  const float* bias = (const float*)d_in[2];
  float* y = (float*)d_out;
  linear_kernel<<<1024, 256, 0, stream>>>(x, w, bias, y);
}

// Round 2
// 245.275 us; speedup vs baseline: 1.0382x; 1.0382x over previous
//
#include <hip/hip_runtime.h>
#include <stdint.h>

// y[m][n] = sum_k x[m][k] * W[k][n] + b[n]
// M=262144, K=128, N=128. Memory-bound: 268 MB @ ~6.3 TB/s ~= 43 us floor.
// bf16 MFMA 16x16x32, operands swapped (A=W^T, B=x) so each lane's 4 C-regs
// are 4 CONSECUTIVE y columns -> f32x4 stores.
//
// R2: R0 structure (grid 2048, 2 iters/block — measured best) but CACHED
// stores instead of nontemporal. Evidence: both R0 and R1 pinned at
// ~1.6-1.7 TB/s of HBM *write* traffic with 12-28% write amplification
// (WRITE_SIZE 150-171 MB vs 134 ideal) -> nt stores stream 64B sectors
// write-through, bypassing L2/L3 write-back coalescing. Each store instr
// covers whole 64B sectors (lanes {c,c+16,c+32,c+48} fill one sector), so
// cached stores need no write-allocate RMW; L2 merges the two 64B halves
// of each 128B line and drains at its own pace.

typedef __attribute__((ext_vector_type(8))) short bf16x8;   // 8 bf16 = 4 VGPRs
typedef __attribute__((ext_vector_type(4))) float f32x4;    // MFMA C/D

__device__ inline unsigned short f2bf(float f) {
  // round-to-nearest-even fp32 -> bf16 (inputs are finite normals)
  union { float f; uint32_t u; } v; v.f = f;
  uint32_t r = v.u + 0x7fffu + ((v.u >> 16) & 1u);
  return (unsigned short)(r >> 16);
}

__global__ __launch_bounds__(256, 4) void linear_kernel(
    const float* __restrict__ x, const float* __restrict__ w,
    const float* __restrict__ bias, float* __restrict__ y) {
  // W in A-fragment order (A = W^T tile):
  //   lds_w[((kk*8+nt)*64 + qk*16+lc)*8 + j] = bf16( W[kk*32+qk*8+j][nt*16+lc] )
  // i.e. A[m=lc][k=qk*8+j] = W[kk*32+k][nt*16+m]
  __shared__ __align__(16) unsigned short lds_w[128 * 128];

  const int t = threadIdx.x;

  // ---- stage W: column-wise scalar reads (L1/L2-hot, sector-coalesced),
  // ---- contiguous ds_write_b128 (conflict-free) ----
  #pragma unroll
  for (int gi = 0; gi < 8; ++gi) {
    int g = t + 256 * gi;            // group 0..2047; one group = 8 shorts = 16 B
    int fragid = g >> 6;             // kk*8+nt
    int slot   = g & 63;             // qk*16+lc
    int kk = fragid >> 3, nt = fragid & 7;
    int qk = slot >> 4,   lc = slot & 15;
    const float* wp = w + (size_t)(kk * 32 + qk * 8) * 128 + nt * 16 + lc;
    unsigned short tmp[8];
    #pragma unroll
    for (int j = 0; j < 8; ++j) tmp[j] = f2bf(wp[(size_t)j * 128]);
    *(bf16x8*)&lds_w[(size_t)g * 8] = *(const bf16x8*)tmp;
  }

  const int lane = t & 63;
  const int wave = t >> 6;
  const int col  = lane & 15;                  // y-row within 16-row tile
  const int quad = lane >> 4;

  // bias fragment: lane's 4 outputs are y cols nt*16 + quad*4 .. +3
  f32x4 bfrag[8];
  #pragma unroll
  for (int nt = 0; nt < 8; ++nt)
    bfrag[nt] = *(const f32x4*)(bias + nt * 16 + quad * 4);

  __syncthreads();

  const int block_row0 = blockIdx.x * 128;     // 128 rows per block

  #pragma unroll
  for (int iter = 0; iter < 2; ++iter) {
    const int row0 = block_row0 + iter * 64 + wave * 16;

    // B fragments (x): lane holds x[row0 + (lane&15)][kk*32 + quad*8 + j]
    const float* xp = x + (size_t)(row0 + col) * 128 + quad * 8;
    bf16x8 xf[4];
    #pragma unroll
    for (int kk = 0; kk < 4; ++kk) {
      f32x4 f0 = *(const f32x4*)(xp + kk * 32);
      f32x4 f1 = *(const f32x4*)(xp + kk * 32 + 4);
      bf16x8 av;
      av[0] = f2bf(f0[0]); av[1] = f2bf(f0[1]); av[2] = f2bf(f0[2]); av[3] = f2bf(f0[3]);
      av[4] = f2bf(f1[0]); av[5] = f2bf(f1[1]); av[6] = f2bf(f1[2]); av[7] = f2bf(f1[3]);
      xf[kk] = av;
    }

    float* yp = y + (size_t)(row0 + col) * 128;
    #pragma unroll
    for (int nt = 0; nt < 8; ++nt) {
      f32x4 acc = bfrag[nt];
      #pragma unroll
      for (int kk = 0; kk < 4; ++kk) {
        bf16x8 wf = *(const bf16x8*)&lds_w[((kk * 8 + nt) * 64 + lane) * 8];
        // D = (W tile)^T . (x tile)^T : D[m][n] = y[row0+n][nt*16+m]
        acc = __builtin_amdgcn_mfma_f32_16x16x32_bf16(wf, xf[kk], acc, 0, 0, 0);
      }
      // lane stores y[row0+col][nt*16 + quad*4 .. +3] as one f32x4 (cached)
      *(f32x4*)(yp + nt * 16 + quad * 4) = acc;
    }
  }
}

extern "C" void kernel_launch(void* const* d_in, const int* in_sizes, int n_in,
                              void* d_out, int out_size, void* d_ws, size_t ws_size,
                              hipStream_t stream) {
  const float* x    = (const float*)d_in[0];
  const float* w    = (const float*)d_in[1];
  const float* bias = (const float*)d_in[2];
  float* y = (float*)d_out;
  linear_kernel<<<2048, 256, 0, stream>>>(x, w, bias, y);
}

// Round 4
// 240.270 us; speedup vs baseline: 1.0599x; 1.0208x over previous
//
#include <hip/hip_runtime.h>
#include <stdint.h>

// y[m][n] = sum_k x[m][k] * W[k][n] + b[n]
// M=262144, K=128, N=128. Memory-bound: 268 MB @ ~6.3 TB/s ~= 43 us floor.
// bf16 MFMA 16x16x32, operands swapped (A=W^T, B=x) so each lane's 4 C-regs
// are 4 CONSECUTIVE y columns -> f32x4 cached stores (R2: nt stores caused
// 12-28% write amplification; cached = exact 133 MB).
//
// R3 (resubmit; previous run died to an infra failure, kernel never ran):
// make the prefetch pipeline REAL. R1's attempt had VGPR=56 -> compiler
// hoisted the f32->bf16 convert (depends only on loads) to right after the
// loads, placing the s_waitcnt BEFORE the MFMA phase = serialized pipeline.
// Fix: sched_barrier(0) fences around the compute phase pin the order
//   issue loads -> [MFMA+stores] -> wait+convert
// Grid 1024 (4 blocks/CU, all resident, no churn), 4 iters/block,
// prefetch distance 1. Iter-0 loads issue before W staging (latency hides
// under the 64 staging loads).

typedef __attribute__((ext_vector_type(8))) short bf16x8;   // 8 bf16 = 4 VGPRs
typedef __attribute__((ext_vector_type(4))) float f32x4;    // MFMA C/D

__device__ inline unsigned short f2bf(float f) {
  // round-to-nearest-even fp32 -> bf16 (inputs are finite normals)
  union { float f; uint32_t u; } v; v.f = f;
  uint32_t r = v.u + 0x7fffu + ((v.u >> 16) & 1u);
  return (unsigned short)(r >> 16);
}

__device__ inline bf16x8 cvt8(f32x4 a, f32x4 b) {
  bf16x8 r;
  r[0] = f2bf(a[0]); r[1] = f2bf(a[1]); r[2] = f2bf(a[2]); r[3] = f2bf(a[3]);
  r[4] = f2bf(b[0]); r[5] = f2bf(b[1]); r[6] = f2bf(b[2]); r[7] = f2bf(b[3]);
  return r;
}

__global__ __launch_bounds__(256, 4) void linear_kernel(
    const float* __restrict__ x, const float* __restrict__ w,
    const float* __restrict__ bias, float* __restrict__ y) {
  // W in A-fragment order (A = W^T tile):
  //   lds_w[((kk*8+nt)*64 + qk*16+lc)*8 + j] = bf16( W[kk*32+qk*8+j][nt*16+lc] )
  __shared__ __align__(16) unsigned short lds_w[128 * 128];

  const int t = threadIdx.x;
  const int lane = t & 63;
  const int wave = t >> 6;
  const int col  = lane & 15;                  // y-row within 16-row tile
  const int quad = lane >> 4;

  // 256 rows per block: 4 iters x 64 rows (16 rows/wave/iter)
  const size_t row0 = (size_t)blockIdx.x * 256 + wave * 16 + col;
  const float* xp = x + row0 * 128 + quad * 8;

  // ---- issue iter-0 x loads FIRST (oldest in vmem queue; latency hides
  // ---- under the W staging below) ----
  f32x4 buf[8];
  #pragma unroll
  for (int kk = 0; kk < 4; ++kk) {
    buf[2 * kk]     = *(const f32x4*)(xp + kk * 32);
    buf[2 * kk + 1] = *(const f32x4*)(xp + kk * 32 + 4);
  }
  __builtin_amdgcn_sched_barrier(0);

  // ---- stage W: column-wise scalar reads (L2-hot), contiguous
  // ---- ds_write_b128 (conflict-free) ----
  #pragma unroll
  for (int gi = 0; gi < 8; ++gi) {
    int g = t + 256 * gi;            // group 0..2047; one group = 8 shorts = 16 B
    int fragid = g >> 6;             // kk*8+nt
    int slot   = g & 63;             // qk*16+lc
    int kk = fragid >> 3, nt = fragid & 7;
    int qk = slot >> 4,   lc = slot & 15;
    const float* wp = w + (size_t)(kk * 32 + qk * 8) * 128 + nt * 16 + lc;
    unsigned short tmp[8];
    #pragma unroll
    for (int j = 0; j < 8; ++j) tmp[j] = f2bf(wp[(size_t)j * 128]);
    *(bf16x8*)&lds_w[(size_t)g * 8] = *(const bf16x8*)tmp;
  }

  // bias fragment: lane's 4 outputs are y cols nt*16 + quad*4 .. +3
  f32x4 bfrag[8];
  #pragma unroll
  for (int nt = 0; nt < 8; ++nt)
    bfrag[nt] = *(const f32x4*)(bias + nt * 16 + quad * 4);

  __syncthreads();

  // convert iter-0 (waits on the prologue loads; already covered by staging)
  bf16x8 xf[4];
  #pragma unroll
  for (int kk = 0; kk < 4; ++kk) xf[kk] = cvt8(buf[2 * kk], buf[2 * kk + 1]);

  #pragma unroll
  for (int it = 0; it < 4; ++it) {
    // ---- issue next iter's loads; MUST stay in flight under the MFMA+store
    // ---- phase below (sched_barrier pins them here) ----
    if (it < 3) {
      const float* xpn = xp + (size_t)(it + 1) * 64 * 128;
      #pragma unroll
      for (int kk = 0; kk < 4; ++kk) {
        buf[2 * kk]     = *(const f32x4*)(xpn + kk * 32);
        buf[2 * kk + 1] = *(const f32x4*)(xpn + kk * 32 + 4);
      }
    }
    __builtin_amdgcn_sched_barrier(0);

    // ---- compute + store current iter (no dependence on the new loads) ----
    float* ypi = y + (row0 + (size_t)it * 64) * 128;
    #pragma unroll
    for (int nt = 0; nt < 8; ++nt) {
      f32x4 acc = bfrag[nt];
      #pragma unroll
      for (int kk = 0; kk < 4; ++kk) {
        bf16x8 wf = *(const bf16x8*)&lds_w[((kk * 8 + nt) * 64 + lane) * 8];
        // D = (W tile)^T . (x tile)^T : D[m][n] = y[row+n][nt*16+m]
        acc = __builtin_amdgcn_mfma_f32_16x16x32_bf16(wf, xf[kk], acc, 0, 0, 0);
      }
      // cached f32x4 store: lanes {c,c+16,c+32,c+48} fill whole 64B sectors
      *(f32x4*)(ypi + nt * 16 + quad * 4) = acc;
    }
    __builtin_amdgcn_sched_barrier(0);

    // ---- NOW wait on the prefetched loads and convert for next iter ----
    if (it < 3) {
      #pragma unroll
      for (int kk = 0; kk < 4; ++kk) xf[kk] = cvt8(buf[2 * kk], buf[2 * kk + 1]);
    }
  }
}

extern "C" void kernel_launch(void* const* d_in, const int* in_sizes, int n_in,
                              void* d_out, int out_size, void* d_ws, size_t ws_size,
                              hipStream_t stream) {
  const float* x    = (const float*)d_in[0];
  const float* w    = (const float*)d_in[1];
  const float* bias = (const float*)d_in[2];
  float* y = (float*)d_out;
  linear_kernel<<<1024, 256, 0, stream>>>(x, w, bias, y);
}

// Round 5
// 234.998 us; speedup vs baseline: 1.0836x; 1.0224x over previous
//
#include <hip/hip_runtime.h>
#include <stdint.h>

// y[m][n] = sum_k x[m][k] * W[k][n] + b[n]
// M=262144, K=128, N=128. 268 MB @ ~6.3 TB/s ~= 43 us floor.
//
// R5: COALESCE EVERYTHING. Evidence: all 4 prior rounds pinned at
// dur ~= WRITE_SIZE / 1.6 TB/s (and logical reads also ~1.6 TB/s) no matter
// the structure; every VMEM instruction was 16 scattered 64B chunks at 512B
// stride (fragment layout). Request-rate/sector-bound, not byte-bound.
// Fix:
//  - x: global_load_lds, each inst = contiguous 1KB (2 full rows), source
//    XOR-pre-swizzled within each 512B row so LDS fragment reads are
//    conflict-free (global coalescing unaffected: wave covers whole rows).
//  - y: acc -> per-wave LDS scratch transpose -> contiguous 1KB stores
//    (full 128B lines only).
//  - per-wave pipeline, no per-iter barriers; iter-1 DMA issued mid-iter-0,
//    waited with counted vmcnt(8) (iter-0 stores stay in flight).
// LDS: W 32KB + x 4x8KB + scratch 4x4KB = 80KB -> 2 blocks/CU.

typedef __attribute__((ext_vector_type(8))) short bf16x8;   // 8 bf16 = 4 VGPRs
typedef __attribute__((ext_vector_type(4))) float f32x4;    // MFMA C/D

__device__ inline unsigned short f2bf(float f) {
  // round-to-nearest-even fp32 -> bf16 (inputs are finite normals)
  union { float f; uint32_t u; } v; v.f = f;
  uint32_t r = v.u + 0x7fffu + ((v.u >> 16) & 1u);
  return (unsigned short)(r >> 16);
}

__device__ inline bf16x8 cvt8(f32x4 a, f32x4 b) {
  bf16x8 r;
  r[0] = f2bf(a[0]); r[1] = f2bf(a[1]); r[2] = f2bf(a[2]); r[3] = f2bf(a[3]);
  r[4] = f2bf(b[0]); r[5] = f2bf(b[1]); r[6] = f2bf(b[2]); r[7] = f2bf(b[3]);
  return r;
}

__device__ inline void gload_lds16(const float* g, float* l) {
  __builtin_amdgcn_global_load_lds(
      (const __attribute__((address_space(1))) unsigned int*)g,
      (__attribute__((address_space(3))) unsigned int*)l, 16, 0, 0);
}

__global__ __launch_bounds__(256, 2) void linear_kernel(
    const float* __restrict__ x, const float* __restrict__ w,
    const float* __restrict__ bias, float* __restrict__ y) {
  // W in A-fragment order: lds_w[(fragid*64 + slot)*8 + j] (unchanged, verified)
  __shared__ __align__(16) unsigned short lds_w[128 * 128];  // 32 KB
  // per-wave x tile: 16 rows x 512B, content lds[r][b] = x[R0+r][b ^ ((r&7)<<4)]
  __shared__ __align__(16) float lds_x[4][2048];             // 4 x 8 KB
  // per-wave store-transpose scratch (half a tile: 4 nt's at a time)
  __shared__ __align__(16) float lds_s[4][1024];             // 4 x 4 KB

  const int t = threadIdx.x;
  const int lane = t & 63;
  const int wave = t >> 6;
  const int col  = lane & 15;                  // lane's y-row within 16-row tile
  const int quad = lane >> 4;

  float* xw = &lds_x[wave][0];
  float* sw = &lds_s[wave][0];

  const size_t blk_row = (size_t)blockIdx.x * 128;   // 128 rows/block, 2 iters

  // ---- issue iter-0 x DMA first (hides under W staging) ----
  #pragma unroll
  for (int i = 0; i < 8; ++i) {
    int r = 2 * i + (lane >> 5);                     // row within wave tile
    int bsrc = ((lane & 31) * 16) ^ ((r & 7) << 4);  // swizzled byte in row
    gload_lds16(x + (blk_row + wave * 16 + r) * 128 + (bsrc >> 2), xw + i * 256);
  }

  // ---- stage W (unchanged; L2-hot, once per block) ----
  #pragma unroll
  for (int gi = 0; gi < 8; ++gi) {
    int g = t + 256 * gi;
    int fragid = g >> 6;             // kk*8+nt
    int slot   = g & 63;             // qk*16+lc
    int kk = fragid >> 3, nt = fragid & 7;
    int qk = slot >> 4,   lc = slot & 15;
    const float* wp = w + (size_t)(kk * 32 + qk * 8) * 128 + nt * 16 + lc;
    unsigned short tmp[8];
    #pragma unroll
    for (int j = 0; j < 8; ++j) tmp[j] = f2bf(wp[(size_t)j * 128]);
    *(bf16x8*)&lds_w[(size_t)g * 8] = *(const bf16x8*)tmp;
  }

  // bias fragment: lane's 4 outputs are y cols nt*16 + quad*4 .. +3
  f32x4 bfrag[8];
  #pragma unroll
  for (int nt = 0; nt < 8; ++nt)
    bfrag[nt] = *(const f32x4*)(bias + nt * 16 + quad * 4);

  __syncthreads();   // lds_w ready (barrier also drains iter-0 DMA)

  #pragma unroll
  for (int it = 0; it < 2; ++it) {
    if (it == 0) { asm volatile("s_waitcnt vmcnt(0)" ::: "memory"); }
    else         { asm volatile("s_waitcnt vmcnt(8)" ::: "memory"); }  // 8 DMAs done; stores in flight

    // ---- x fragments from swizzled LDS (2-way conflicts = free) ----
    bf16x8 xf[4];
    #pragma unroll
    for (int kk = 0; kk < 4; ++kk) {
      int blog = quad * 32 + kk * 128;                 // logical byte in row
      int sz = (col & 7) << 4;
      f32x4 a = *(const f32x4*)(xw + col * 128 + ((blog ^ sz) >> 2));
      f32x4 b = *(const f32x4*)(xw + col * 128 + (((blog + 16) ^ sz) >> 2));
      xf[kk] = cvt8(a, b);
    }

    // ---- prefetch iter-1 x DMA (frag reads consumed; WAR-safe) ----
    if (it == 0) {
      #pragma unroll
      for (int i = 0; i < 8; ++i) {
        int r = 2 * i + (lane >> 5);
        int bsrc = ((lane & 31) * 16) ^ ((r & 7) << 4);
        gload_lds16(x + (blk_row + 64 + wave * 16 + r) * 128 + (bsrc >> 2),
                    xw + i * 256);
      }
    }

    // ---- MFMA: acc[nt] = y[row0+col][nt*16 + quad*4 .. +3] ----
    f32x4 acc[8];
    #pragma unroll
    for (int nt = 0; nt < 8; ++nt) {
      acc[nt] = bfrag[nt];
      #pragma unroll
      for (int kk = 0; kk < 4; ++kk) {
        bf16x8 wf = *(const bf16x8*)&lds_w[((kk * 8 + nt) * 64 + lane) * 8];
        acc[nt] = __builtin_amdgcn_mfma_f32_16x16x32_bf16(wf, xf[kk], acc[nt], 0, 0, 0);
      }
    }

    // ---- store-transpose: scratch round-trip -> contiguous 1KB stores ----
    // scratch addr for y[r][c] (c = (4h+n)*16 + q*4 + j, owner lane l0=r+16q):
    //   (r+16q)*64B + (n*16 ^ ((r&3)<<4)) + 4j
    float* yb = y + (blk_row + it * 64 + wave * 16) * 128;
    #pragma unroll
    for (int h = 0; h < 2; ++h) {
      #pragma unroll
      for (int n = 0; n < 4; ++n)
        *(f32x4*)(sw + lane * 16 + (((n * 16) ^ ((lane & 3) << 4)) >> 2)) = acc[4 * h + n];
      // compiler inserts lgkmcnt waits (may-alias LDS)
      #pragma unroll
      for (int s = 0; s < 4; ++s) {
        int r = 4 * s + (lane >> 4);          // 4 rows per store inst
        int n = (lane & 15) >> 2;
        int q = (lane & 15) & 3;
        f32x4 v = *(const f32x4*)(sw + (r + 16 * q) * 16 +
                                  (((n * 16) ^ ((r & 3) << 4)) >> 2));
        // lanes (lane&15)=0..15 cover a contiguous 256B row-half; inst = 1KB
        *(f32x4*)(yb + r * 128 + h * 64 + (lane & 15) * 4) = v;
      }
    }
  }
}

extern "C" void kernel_launch(void* const* d_in, const int* in_sizes, int n_in,
                              void* d_out, int out_size, void* d_ws, size_t ws_size,
                              hipStream_t stream) {
  const float* x    = (const float*)d_in[0];
  const float* w    = (const float*)d_in[1];
  const float* bias = (const float*)d_in[2];
  float* y = (float*)d_out;
  linear_kernel<<<2048, 256, 0, stream>>>(x, w, bias, y);
}